// Round 7
// baseline (40.231 us; speedup 1.0000x reference)
//
#include <hip/hip_runtime.h>

#define BS 8
#define NN 1024
#define JJ 4
#define FF 32
#define NC 2

#define THREADS 512   // 8 waves
#define ROWS 16       // output rows per block -> 512 blocks = 2 blocks/CU

typedef float f4v __attribute__((ext_vector_type(4)));

// Fully fused, 2 blocks/CU:
//   out[b,n,c] = sum_m sum_j WW[b,n,m,j] * y[b,m,j,c] + fc_b[c]
//   y[b,m,j,c] = sum_f x[b,m,f] * fc_w[c, j*FF+f]
// Phase 1: block computes full y[b] into LDS (2 m per thread, 512 FMA,
//          float4 x loads, fc_w uniform -> scalar loads). Redundant across the
//          64 blocks sharing b (~1.7 us chip-equivalent, hidden under stream).
// Phase 2: R2's proven stream — wave owns 2 rows, float4 WW loads, y from LDS.
// Two resident blocks per CU overlap each other's serial phases.
__global__ void __launch_bounds__(THREADS, 4) fused_gmul_fc_kernel(
    const float* __restrict__ WW, const float* __restrict__ x,
    const float* __restrict__ fc_w, const float* __restrict__ fc_b,
    float* __restrict__ out) {
    __shared__ float4 lyA[NN];  // (j0c0,j0c1,j1c0,j1c1) per m
    __shared__ float4 lyB[NN];  // (j2c0,j2c1,j3c0,j3c1) per m

    const int blk  = blockIdx.x;      // 0..511
    const int b    = blk >> 6;        // 64 blocks per batch element
    const int tid  = threadIdx.x;     // 0..511
    const int wave = tid >> 6;
    const int lane = tid & 63;

    // ---- Phase 1: y[b][m] -> LDS, m in {tid, tid+512} ----
#pragma unroll
    for (int h = 0; h < 2; ++h) {
        const int m = tid + h * THREADS;
        const float4* xr =
            reinterpret_cast<const float4*>(x + ((size_t)b * NN + m) * FF);
        float xv[FF];
#pragma unroll
        for (int q = 0; q < FF / 4; ++q) {
            float4 v = xr[q];
            xv[4 * q + 0] = v.x; xv[4 * q + 1] = v.y;
            xv[4 * q + 2] = v.z; xv[4 * q + 3] = v.w;
        }
        float a[JJ][NC];
#pragma unroll
        for (int j = 0; j < JJ; ++j) {
            float s0 = 0.f, s1 = 0.f;
            const float* w0 = fc_w + 0 * (JJ * FF) + j * FF;  // uniform
            const float* w1 = fc_w + 1 * (JJ * FF) + j * FF;
#pragma unroll
            for (int f = 0; f < FF; ++f) {
                float xf = xv[f];
                s0 += xf * w0[f];
                s1 += xf * w1[f];
            }
            a[j][0] = s0; a[j][1] = s1;
        }
        lyA[m] = make_float4(a[0][0], a[0][1], a[1][0], a[1][1]);
        lyB[m] = make_float4(a[2][0], a[2][1], a[3][0], a[3][1]);
    }
    __syncthreads();

    // ---- Phase 2: stream WW, 2 rows per wave ----
    const int row0 = blk * ROWS + wave * 2;   // global row = b*NN + n
    const f4v* W0 = reinterpret_cast<const f4v*>(WW) + (size_t)row0 * NN;
    const f4v* W1 = W0 + NN;

    float s00 = 0.f, s01 = 0.f, s10 = 0.f, s11 = 0.f;
#pragma unroll 4
    for (int m = lane; m < NN; m += 64) {
        f4v w0 = W0[m];
        f4v w1 = W1[m];
        float4 ya = lyA[m];
        float4 yb = lyB[m];
        s00 += w0.x * ya.x + w0.y * ya.z + w0.z * yb.x + w0.w * yb.z;
        s01 += w0.x * ya.y + w0.y * ya.w + w0.z * yb.y + w0.w * yb.w;
        s10 += w1.x * ya.x + w1.y * ya.z + w1.z * yb.x + w1.w * yb.z;
        s11 += w1.x * ya.y + w1.y * ya.w + w1.z * yb.y + w1.w * yb.w;
    }
#pragma unroll
    for (int off = 32; off > 0; off >>= 1) {
        s00 += __shfl_down(s00, off, 64);
        s01 += __shfl_down(s01, off, 64);
        s10 += __shfl_down(s10, off, 64);
        s11 += __shfl_down(s11, off, 64);
    }
    if (lane == 0) {
        float b0 = fc_b[0], b1 = fc_b[1];
        out[(size_t)row0 * NC + 0] = s00 + b0;
        out[(size_t)row0 * NC + 1] = s01 + b1;
        out[(size_t)(row0 + 1) * NC + 0] = s10 + b0;
        out[(size_t)(row0 + 1) * NC + 1] = s11 + b1;
    }
}

extern "C" void kernel_launch(void* const* d_in, const int* in_sizes, int n_in,
                              void* d_out, int out_size, void* d_ws, size_t ws_size,
                              hipStream_t stream) {
    const float* WW   = (const float*)d_in[0];  // (BS, NN, NN, JJ) fp32
    const float* x    = (const float*)d_in[1];  // (BS, NN, FF) fp32
    const float* fc_w = (const float*)d_in[2];  // (NC, JJ*FF) fp32
    const float* fc_b = (const float*)d_in[3];  // (NC,) fp32
    float* out = (float*)d_out;                 // (BS, NN, NC) fp32

    const int blocks = (BS * NN) / ROWS;  // 512 blocks -> 2 per CU
    fused_gmul_fc_kernel<<<blocks, THREADS, 0, stream>>>(WW, x, fc_w, fc_b, out);
}

// Round 8
// 30.909 us; speedup vs baseline: 1.3016x; 1.3016x over previous
//
#include <hip/hip_runtime.h>

#define BS 8
#define NN 1024
#define JJ 4
#define FF 32
#define NC 2

typedef float f4v __attribute__((ext_vector_type(4)));

// y[b][m][j][c] = sum_f x[b,m,f] * fc_w[c, j*FF+f]
// Deinterleaved: yA[bm] = (j0c0,j0c1,j1c0,j1c1), yB[bm] = (j2c0,j2c1,j3c0,j3c1)
// One thread per (b,m,j). Fully vectorized: 8 float4 x-loads + 16 float4
// fc_w loads (L1-broadcast, 1 KB total) + 64 packed FMA pairs.
__global__ void __launch_bounds__(256) compute_y_kernel(
    const float* __restrict__ x, const float* __restrict__ fc_w,
    float2* __restrict__ yA, float2* __restrict__ yB) {
    int idx = blockIdx.x * blockDim.x + threadIdx.x;  // BS*NN*JJ = 32768
    int j  = idx & (JJ - 1);
    int bm = idx >> 2;                 // b*NN + m

    const f4v* xr = reinterpret_cast<const f4v*>(x + (size_t)bm * FF);       // 128B-aligned
    const f4v* w0 = reinterpret_cast<const f4v*>(fc_w + j * FF);             // class 0
    const f4v* w1 = reinterpret_cast<const f4v*>(fc_w + JJ * FF + j * FF);   // class 1

    float a0 = 0.f, a1 = 0.f;
#pragma unroll
    for (int q = 0; q < FF / 4; ++q) {
        f4v xv = xr[q];
        f4v v0 = w0[q];
        f4v v1 = w1[q];
        a0 += xv.x * v0.x + xv.y * v0.y + xv.z * v0.z + xv.w * v0.w;
        a1 += xv.x * v1.x + xv.y * v1.y + xv.z * v1.z + xv.w * v1.w;
    }
    float2 v = make_float2(a0, a1);
    if (j < 2) yA[bm * 2 + j]       = v;
    else       yB[bm * 2 + (j - 2)] = v;
}

// out[b,n,c] = sum_m sum_j WW[b,n,m,j] * y[b,m,j,c] + fc_b[c]
// R2 structure verbatim (best measured): 4 waves/block, 2 rows/wave,
// y[b] staged in LDS, nontemporal float4 WW stream.
__global__ void __launch_bounds__(256) reduce_out_kernel(
    const float* __restrict__ WW, const float4* __restrict__ yA,
    const float4* __restrict__ yB, const float* __restrict__ fc_b,
    float* __restrict__ out) {
    __shared__ float4 lyA[NN];
    __shared__ float4 lyB[NN];

    const int blk  = blockIdx.x;          // 0..1023
    const int b    = blk >> 7;            // 128 blocks per batch element
    const int wave = threadIdx.x >> 6;
    const int lane = threadIdx.x & 63;

    for (int i = threadIdx.x; i < NN; i += 256) {
        lyA[i] = yA[(size_t)b * NN + i];
        lyB[i] = yB[(size_t)b * NN + i];
    }
    __syncthreads();

    const int row0 = blk * 8 + wave * 2;  // global row = b*NN + n
    const f4v* W0 = reinterpret_cast<const f4v*>(WW) + (size_t)row0 * NN;
    const f4v* W1 = W0 + NN;

    float a00 = 0.f, a01 = 0.f, a10 = 0.f, a11 = 0.f;
#pragma unroll 4
    for (int m = lane; m < NN; m += 64) {
        f4v w0 = __builtin_nontemporal_load(W0 + m);
        f4v w1 = __builtin_nontemporal_load(W1 + m);
        float4 ya = lyA[m];
        float4 yb = lyB[m];
        a00 += w0.x * ya.x + w0.y * ya.z + w0.z * yb.x + w0.w * yb.z;
        a01 += w0.x * ya.y + w0.y * ya.w + w0.z * yb.y + w0.w * yb.w;
        a10 += w1.x * ya.x + w1.y * ya.z + w1.z * yb.x + w1.w * yb.z;
        a11 += w1.x * ya.y + w1.y * ya.w + w1.z * yb.y + w1.w * yb.w;
    }
#pragma unroll
    for (int off = 32; off > 0; off >>= 1) {
        a00 += __shfl_down(a00, off, 64);
        a01 += __shfl_down(a01, off, 64);
        a10 += __shfl_down(a10, off, 64);
        a11 += __shfl_down(a11, off, 64);
    }
    if (lane == 0) {
        float b0 = fc_b[0], b1 = fc_b[1];
        out[(size_t)row0 * NC + 0] = a00 + b0;
        out[(size_t)row0 * NC + 1] = a01 + b1;
        out[(size_t)(row0 + 1) * NC + 0] = a10 + b0;
        out[(size_t)(row0 + 1) * NC + 1] = a11 + b1;
    }
}

extern "C" void kernel_launch(void* const* d_in, const int* in_sizes, int n_in,
                              void* d_out, int out_size, void* d_ws, size_t ws_size,
                              hipStream_t stream) {
    const float* WW   = (const float*)d_in[0];  // (BS, NN, NN, JJ) fp32
    const float* x    = (const float*)d_in[1];  // (BS, NN, FF) fp32
    const float* fc_w = (const float*)d_in[2];  // (NC, JJ*FF) fp32
    const float* fc_b = (const float*)d_in[3];  // (NC,) fp32
    float* out = (float*)d_out;                 // (BS, NN, NC) fp32

    float* ws   = (float*)d_ws;
    float2* yA2 = (float2*)ws;
    float2* yB2 = (float2*)(ws + (size_t)BS * NN * 4);

    {
        int total = BS * NN * JJ;                       // 32768, exact multiple of 256
        compute_y_kernel<<<total / 256, 256, 0, stream>>>(x, fc_w, yA2, yB2);
    }
    {
        int blocks = (BS * NN) / 8;  // 1024
        reduce_out_kernel<<<blocks, 256, 0, stream>>>(
            WW, (const float4*)yA2, (const float4*)yB2, fc_b, out);
    }
}